// Round 2
// baseline (1049.424 us; speedup 1.0000x reference)
//
#include <hip/hip_runtime.h>

// PoolAggregator fused, MFMA (bf16 in / f32 acc) version.
//   k0: zero stat slots + pre-transpose Ws/Wn to bf16 [col][k] (replaces memset + enables
//       vector B-frag loads in K2).
//   K1: x = neigh@Wt + bt, track per-node max/min over k (25 rows padded to 32)
//       plus BN1 column sums — the [1.25M,256] tensor never hits HBM.
//       max/min packed 2xbf16 into one u32 per (node,col): halves the round-trip traffic.
//   K2: computes BN1 affine (a1,c1) from slot stats in-prologue (k_stats#1 folded in).
//       pool(BN(x)) = a>=0 ? a*max+c : a*min+c.  [self@Ws | pooled@Wn] via MFMA,
//       writes pre-BN Y to d_out + BN2 column sums.
//   k7: out = relu(a2*Y + c2) in place.

#define NN 50000
#define KN 25
#define FIN 128
#define TD 256
#define OUTD 128
#define BN_EPS 1e-3f
#define NSLOTS 64
#define K1_GRID 512
#define NGROUPS (NN / 2)   // 2 nodes per group

typedef float f32x4 __attribute__((ext_vector_type(4)));
typedef short bf16x8 __attribute__((ext_vector_type(8)));

__device__ __forceinline__ ushort f2bf(float f) {
    uint u = __builtin_bit_cast(uint, f);
    return (ushort)((u + 0x7FFFu + ((u >> 16) & 1u)) >> 16);
}
__device__ __forceinline__ uint pk2(float a, float b) {
    return (uint)f2bf(a) | ((uint)f2bf(b) << 16);
}
__device__ __forceinline__ float bflo(uint u) {   // low half -> f32
    return __builtin_bit_cast(float, u << 16);
}
__device__ __forceinline__ float bfhi(uint u) {   // high half -> f32
    return __builtin_bit_cast(float, u & 0xffff0000u);
}

// ============ k0: zero stats + transpose weights to bf16 [col][k] ============
// 65536 zero-floats (4 stat arrays) + 16384 WsT + 32768 WnT = 114688 items = 448 blocks.
__global__ __launch_bounds__(256) void k0_prep(
    const float* __restrict__ Ws, const float* __restrict__ Wn,
    float* __restrict__ stats, ushort* __restrict__ WsT, ushort* __restrict__ WnT)
{
    const int gid = blockIdx.x * 256 + threadIdx.x;
    if (gid < 65536) {
        stats[gid] = 0.f;
    } else if (gid < 81920) {
        const int t = gid - 65536, col = t >> 7, k = t & 127;
        WsT[col * FIN + k] = f2bf(Ws[k * OUTD + col]);
    } else {
        const int t = gid - 81920, col = t >> 8, k = t & 255;
        WnT[col * TD + k] = f2bf(Wn[k * OUTD + col]);
    }
}

// ============ K1: GEMM1 + pool-prep + BN1 stats ============
// Block: 256 thr (4 waves), persistent. Group = 2 nodes = 50 real rows,
// padded to 64 (node g at padded rows 32g..32g+31; rows 25..31 are garbage,
// masked in epilogue — MFMA rows are independent so garbage can't leak).
// LDS 64 KB exactly: Wt staged bf16 [128][256] once, B-frags -> regs,
// then region reused as 2x double-buffered A [64 rows][136] bf16 (pad +8
// breaks the 256B-stride bank alias; frag b128 pattern lands min-conflict).
__global__ __launch_bounds__(256, 2) void k1_gemm_pool(
    const float* __restrict__ neigh, const float* __restrict__ Wt,
    const float* __restrict__ bt, uint* __restrict__ nmm,
    float* __restrict__ s1sum, float* __restrict__ s1sq)
{
    __shared__ ushort lds[32768];   // 65536 B
    const int tid = threadIdx.x;
    const int wave = tid >> 6, lane = tid & 63;
    const int quad = lane >> 4, l16 = lane & 15;
    const int cbase = wave * 64;

    // ---- stage Wt -> LDS bf16, row-major [k][col] ----
    {
        const float4* w4 = (const float4*)Wt;     // 8192 float4
        #pragma unroll
        for (int i = 0; i < 32; ++i) {
            const int e = tid + i * 256;
            const int k = e >> 6, c4 = (e & 63) << 2;
            const float4 v = w4[e];
            uint* dst = (uint*)&lds[k * 256 + c4];
            dst[0] = pk2(v.x, v.y);
            dst[1] = pk2(v.z, v.w);
        }
    }
    __syncthreads();

    // ---- B-frags to regs: bf[nt][ks][j] = B[ks*32+quad*8+j][cbase+nt*16+l16] ----
    bf16x8 bf[4][4];
    #pragma unroll
    for (int nt = 0; nt < 4; ++nt) {
        const int col = cbase + nt * 16 + l16;
        #pragma unroll
        for (int ks = 0; ks < 4; ++ks) {
            #pragma unroll
            for (int j = 0; j < 8; ++j)
                bf[nt][ks][j] = (short)lds[(ks * 32 + quad * 8 + j) * 256 + col];
        }
    }
    __syncthreads();   // before A staging overwrites the B region

    float bv[4];
    #pragma unroll
    for (int n = 0; n < 4; ++n) bv[n] = bt[cbase + n * 16 + l16];

    float S[4] = {0.f, 0.f, 0.f, 0.f}, Q[4] = {0.f, 0.f, 0.f, 0.f};

    // ---- preload first group into buf 0 (float4: 1600 per group) ----
    int g = blockIdx.x;
    {
        const float4* src = (const float4*)(neigh + (size_t)g * 6400);
        #pragma unroll
        for (int i = 0; i < 7; ++i) {
            const int idx = tid + i * 256;
            if (idx < 1600) {
                const float4 v = src[idx];
                const int r = idx >> 5;
                const int pr = r + (r >= 25 ? 7 : 0);   // node1 -> padded rows 32+
                uint* dst = (uint*)&lds[pr * 136 + ((idx & 31) << 2)];
                dst[0] = pk2(v.x, v.y);
                dst[1] = pk2(v.z, v.w);
            }
        }
    }
    __syncthreads();

    int cur = 0;
    for (; g < NGROUPS; g += K1_GRID) {
        const int gn = g + K1_GRID;
        // prefetch next group's A into regs (overlaps with MFMA below)
        float4 pre[7];
        if (gn < NGROUPS) {
            const float4* src = (const float4*)(neigh + (size_t)gn * 6400);
            #pragma unroll
            for (int i = 0; i < 7; ++i) {
                const int idx = tid + i * 256;
                if (idx < 1600) pre[i] = src[idx];
            }
        }
        // ---- MFMA: 4 m-tiles x 4 n-tiles x 4 k-slices ----
        const ushort* Ab = lds + cur * 8704;
        f32x4 acc[4][4];
        #pragma unroll
        for (int m = 0; m < 4; ++m)
            #pragma unroll
            for (int n = 0; n < 4; ++n)
                acc[m][n] = (f32x4){0.f, 0.f, 0.f, 0.f};
        #pragma unroll
        for (int m = 0; m < 4; ++m) {
            bf16x8 af[4];
            #pragma unroll
            for (int ks = 0; ks < 4; ++ks)
                af[ks] = *(const bf16x8*)&Ab[(m * 16 + l16) * 136 + ks * 32 + quad * 8];
            #pragma unroll
            for (int n = 0; n < 4; ++n)
                #pragma unroll
                for (int ks = 0; ks < 4; ++ks)
                    acc[m][n] = __builtin_amdgcn_mfma_f32_16x16x32_bf16(af[ks], bf[n][ks], acc[m][n], 0, 0, 0);
        }
        // ---- epilogue: per node (m-tiles {2g,2g+1}), mask padded rows ----
        // C layout: col = lane&15, row = quad*4 + reg (m89-verified).
        // m even: rows 0..15 all real. m odd: row 16+quad*4+i valid iff quad*4+i<9.
        #pragma unroll
        for (int gi = 0; gi < 2; ++gi) {
            const int node = g * 2 + gi;
            #pragma unroll
            for (int n = 0; n < 4; ++n) {
                float mx = -3.4e38f, mn = 3.4e38f;
                #pragma unroll
                for (int i = 0; i < 4; ++i) {
                    const float v = acc[2 * gi][n][i] + bv[n];
                    mx = fmaxf(mx, v); mn = fminf(mn, v);
                    S[n] += v; Q[n] = fmaf(v, v, Q[n]);
                }
                #pragma unroll
                for (int i = 0; i < 4; ++i) {
                    if (quad * 4 + i < 9) {
                        const float v = acc[2 * gi + 1][n][i] + bv[n];
                        mx = fmaxf(mx, v); mn = fminf(mn, v);
                        S[n] += v; Q[n] = fmaf(v, v, Q[n]);
                    }
                }
                mx = fmaxf(mx, __shfl_xor(mx, 16)); mx = fmaxf(mx, __shfl_xor(mx, 32));
                mn = fminf(mn, __shfl_xor(mn, 16)); mn = fminf(mn, __shfl_xor(mn, 32));
                if (lane < 16)
                    nmm[node * TD + cbase + n * 16 + lane] = pk2(mx, mn);  // lo=max, hi=min
            }
        }
        // ---- write prefetched A into the other buffer ----
        if (gn < NGROUPS) {
            ushort* Aw = lds + (cur ^ 1) * 8704;
            #pragma unroll
            for (int i = 0; i < 7; ++i) {
                const int idx = tid + i * 256;
                if (idx < 1600) {
                    const int r = idx >> 5;
                    const int pr = r + (r >= 25 ? 7 : 0);
                    uint* dst = (uint*)&Aw[pr * 136 + ((idx & 31) << 2)];
                    dst[0] = pk2(pre[i].x, pre[i].y);
                    dst[1] = pk2(pre[i].z, pre[i].w);
                }
            }
        }
        __syncthreads();
        cur ^= 1;
    }
    // ---- flush BN1 stats (once per block) ----
    #pragma unroll
    for (int n = 0; n < 4; ++n) {
        float s = S[n]; s += __shfl_xor(s, 16); s += __shfl_xor(s, 32);
        float q = Q[n]; q += __shfl_xor(q, 16); q += __shfl_xor(q, 32);
        if (lane < 16) {
            const int col = cbase + n * 16 + lane;
            const int slot = blockIdx.x & (NSLOTS - 1);
            atomicAdd(&s1sum[slot * TD + col], s);
            atomicAdd(&s1sq[slot * TD + col], q);
        }
    }
}

// ============ slot stats -> BN affine coefficients (used for BN2 only now) ============
__global__ __launch_bounds__(256) void k_stats(
    const float* __restrict__ ssum, const float* __restrict__ ssq,
    const float* __restrict__ g, const float* __restrict__ b,
    float invM, float* __restrict__ a, float* __restrict__ cc)
{
    const int c = threadIdx.x;
    float s = 0.f, q = 0.f;
    for (int j = 0; j < NSLOTS; ++j) { s += ssum[j * TD + c]; q += ssq[j * TD + c]; }
    const float mean = s * invM;
    const float var = q * invM - mean * mean;
    const float A = rsqrtf(var + BN_EPS) * g[c];
    a[c] = A;
    cc[c] = fmaf(-mean, A, b[c]);
}

// ============ K2: [self@Ws | pooled@Wn] MFMA, Y (pre-BN2) -> d_out + stats ============
// Block: 64 rows, 4 waves. Waves 0,1: self GEMM (K=128); waves 2,3: pooled (K=256).
// Output col base = wave*64 (matches concat order). B-frags: 16B vector loads from
// pre-transposed bf16 WsT/WnT (L2-hot). BN1 affine computed in-prologue from slot stats.
__global__ __launch_bounds__(256, 2) void k2_gemm2(
    const float* __restrict__ selfn, const uint* __restrict__ nmm,
    const ushort* __restrict__ WsT, const ushort* __restrict__ WnT,
    const float* __restrict__ s1sum, const float* __restrict__ s1sq,
    const float* __restrict__ g1, const float* __restrict__ b1,
    float* __restrict__ Y, float* __restrict__ s2sum, float* __restrict__ s2sq)
{
    __shared__ ushort lds[25600];   // As[64][136] @0 (17408B), Ap[64][264] @8704 (33792B)
    __shared__ float aL[256], cL[256];
    const int tid = threadIdx.x;
    const int wave = tid >> 6, lane = tid & 63;
    const int quad = lane >> 4, l16 = lane & 15;
    const int R0 = blockIdx.x * 64;

    // BN1 affine from slot stats (k_stats#1 folded in; redundant per block, L2-hot)
    {
        const int c = tid;
        float s = 0.f, q = 0.f;
        #pragma unroll 8
        for (int j = 0; j < NSLOTS; ++j) { s += s1sum[j * TD + c]; q += s1sq[j * TD + c]; }
        const float invM = 1.f / (float)((size_t)NN * KN);
        const float mean = s * invM;
        const float var = q * invM - mean * mean;
        const float A = rsqrtf(var + BN_EPS) * g1[c];
        aL[c] = A;
        cL[c] = fmaf(-mean, A, b1[c]);
    }

    // stage self -> As (bf16); no aL dependency, runs before the barrier
    {
        const float4* s4 = (const float4*)selfn;
        #pragma unroll
        for (int i = 0; i < 8; ++i) {
            const int e = tid + i * 256;          // < 2048
            const int r = e >> 5, k4 = e & 31;
            const int gr = R0 + r;
            const float4 v = (gr < NN) ? s4[(size_t)gr * 32 + k4] : make_float4(0.f, 0.f, 0.f, 0.f);
            uint* dst = (uint*)&lds[r * 136 + (k4 << 2)];
            dst[0] = pk2(v.x, v.y);
            dst[1] = pk2(v.z, v.w);
        }
    }
    __syncthreads();   // aL/cL visible to all

    // stage pooled -> Ap: pooled = a1>=0 ? a1*max+c1 : a1*min+c1, to bf16
    // nmm element: lo bf16 = max, hi bf16 = min.
    {
        const uint4* m4 = (const uint4*)nmm;
        #pragma unroll
        for (int i = 0; i < 16; ++i) {
            const int e = tid + i * 256;          // < 4096
            const int r = e >> 6, c4 = e & 63;
            const int gr = R0 + r;
            uint4 v;
            if (gr < NN) v = m4[(size_t)gr * 64 + c4];
            else { v.x = 0u; v.y = 0u; v.z = 0u; v.w = 0u; }
            const float4 a = *(const float4*)&aL[c4 << 2];
            const float4 c = *(const float4*)&cL[c4 << 2];
            const float p0 = (a.x >= 0.f) ? fmaf(a.x, bflo(v.x), c.x) : fmaf(a.x, bfhi(v.x), c.x);
            const float p1 = (a.y >= 0.f) ? fmaf(a.y, bflo(v.y), c.y) : fmaf(a.y, bfhi(v.y), c.y);
            const float p2 = (a.z >= 0.f) ? fmaf(a.z, bflo(v.z), c.z) : fmaf(a.z, bfhi(v.z), c.z);
            const float p3 = (a.w >= 0.f) ? fmaf(a.w, bflo(v.w), c.w) : fmaf(a.w, bfhi(v.w), c.w);
            uint* dst = (uint*)&lds[8704 + r * 264 + (c4 << 2)];
            dst[0] = pk2(p0, p1);
            dst[1] = pk2(p2, p3);
        }
    }
    __syncthreads();

    f32x4 acc[4][4];
    #pragma unroll
    for (int m = 0; m < 4; ++m)
        #pragma unroll
        for (int n = 0; n < 4; ++n)
            acc[m][n] = (f32x4){0.f, 0.f, 0.f, 0.f};

    if (wave < 2) {
        const int cb = wave * 64;
        bf16x8 bfr[4][4];
        #pragma unroll
        for (int nt = 0; nt < 4; ++nt)
            #pragma unroll
            for (int ks = 0; ks < 4; ++ks)
                bfr[nt][ks] = *(const bf16x8*)&WsT[(cb + nt * 16 + l16) * FIN + ks * 32 + quad * 8];
        #pragma unroll
        for (int m = 0; m < 4; ++m) {
            bf16x8 af[4];
            #pragma unroll
            for (int ks = 0; ks < 4; ++ks)
                af[ks] = *(const bf16x8*)&lds[(m * 16 + l16) * 136 + ks * 32 + quad * 8];
            #pragma unroll
            for (int nt = 0; nt < 4; ++nt)
                #pragma unroll
                for (int ks = 0; ks < 4; ++ks)
                    acc[m][nt] = __builtin_amdgcn_mfma_f32_16x16x32_bf16(af[ks], bfr[nt][ks], acc[m][nt], 0, 0, 0);
        }
    } else {
        const int cb = (wave - 2) * 64;
        bf16x8 bfr[4][8];
        #pragma unroll
        for (int nt = 0; nt < 4; ++nt)
            #pragma unroll
            for (int ks = 0; ks < 8; ++ks)
                bfr[nt][ks] = *(const bf16x8*)&WnT[(cb + nt * 16 + l16) * TD + ks * 32 + quad * 8];
        #pragma unroll
        for (int m = 0; m < 4; ++m) {
            bf16x8 af[8];
            #pragma unroll
            for (int ks = 0; ks < 8; ++ks)
                af[ks] = *(const bf16x8*)&lds[8704 + (m * 16 + l16) * 264 + ks * 32 + quad * 8];
            #pragma unroll
            for (int nt = 0; nt < 4; ++nt)
                #pragma unroll
                for (int ks = 0; ks < 8; ++ks)
                    acc[m][nt] = __builtin_amdgcn_mfma_f32_16x16x32_bf16(af[ks], bfr[nt][ks], acc[m][nt], 0, 0, 0);
        }
    }

    // epilogue: Y (pre-BN2) + column stats
    const int colb = wave * 64;
    float S[4] = {0.f, 0.f, 0.f, 0.f}, Q[4] = {0.f, 0.f, 0.f, 0.f};
    #pragma unroll
    for (int m = 0; m < 4; ++m) {
        #pragma unroll
        for (int nt = 0; nt < 4; ++nt) {
            #pragma unroll
            for (int i = 0; i < 4; ++i) {
                const int row = R0 + m * 16 + quad * 4 + i;
                const float v = acc[m][nt][i];
                if (row < NN) {
                    Y[(size_t)row * TD + colb + nt * 16 + l16] = v;
                    S[nt] += v;
                    Q[nt] = fmaf(v, v, Q[nt]);
                }
            }
        }
    }
    #pragma unroll
    for (int nt = 0; nt < 4; ++nt) {
        float s = S[nt]; s += __shfl_xor(s, 16); s += __shfl_xor(s, 32);
        float q = Q[nt]; q += __shfl_xor(q, 16); q += __shfl_xor(q, 32);
        if (lane < 16) {
            const int col = colb + nt * 16 + lane;
            const int slot = blockIdx.x & (NSLOTS - 1);
            atomicAdd(&s2sum[slot * TD + col], s);
            atomicAdd(&s2sq[slot * TD + col], q);
        }
    }
}

// ============ K7: out = relu(a2*Y + c2), in place on d_out ============
__global__ __launch_bounds__(256) void k7_bn_relu(
    float* __restrict__ out, const float* __restrict__ a2, const float* __restrict__ c2)
{
    const int idx = blockIdx.x * 256 + threadIdx.x;   // float4 index, N*TD/4
    const int c4 = idx & 63;
    float4 y = ((const float4*)out)[idx];
    const float4 a = ((const float4*)a2)[c4];
    const float4 c = ((const float4*)c2)[c4];
    y.x = fmaxf(0.f, fmaf(a.x, y.x, c.x));
    y.y = fmaxf(0.f, fmaf(a.y, y.y, c.y));
    y.z = fmaxf(0.f, fmaf(a.z, y.z, c.z));
    y.w = fmaxf(0.f, fmaf(a.w, y.w, c.w));
    ((float4*)out)[idx] = y;
}

extern "C" void kernel_launch(void* const* d_in, const int* in_sizes, int n_in,
                              void* d_out, int out_size, void* d_ws, size_t ws_size,
                              hipStream_t stream) {
    const float* selfn = (const float*)d_in[0];
    const float* neigh = (const float*)d_in[1];
    // d_in[2] = len_adj_nodes: unused by the reference
    const float* Wt = (const float*)d_in[3];
    const float* bt = (const float*)d_in[4];
    const float* g1 = (const float*)d_in[5];
    const float* b1 = (const float*)d_in[6];
    const float* Wn = (const float*)d_in[7];
    const float* Ws = (const float*)d_in[8];
    const float* g2 = (const float*)d_in[9];
    const float* b2 = (const float*)d_in[10];
    float* out = (float*)d_out;

    // ws layout: nmm[N*T] u32 | s1sum,s1sq,s2sum,s2sq [64*T each] | a2,c2 | WsT,WnT bf16
    float* ws = (float*)d_ws;
    uint* nmm = (uint*)ws;
    float* s1sum = ws + (size_t)NN * TD;
    float* s1sq = s1sum + NSLOTS * TD;
    float* s2sum = s1sq + NSLOTS * TD;
    float* s2sq = s2sum + NSLOTS * TD;
    float* a2 = s2sq + NSLOTS * TD;
    float* c2 = a2 + TD;
    ushort* WsT = (ushort*)(c2 + TD);
    ushort* WnT = WsT + FIN * OUTD;

    k0_prep<<<448, 256, 0, stream>>>(Ws, Wn, s1sum, WsT, WnT);
    k1_gemm_pool<<<K1_GRID, 256, 0, stream>>>(neigh, Wt, bt, nmm, s1sum, s1sq);
    k2_gemm2<<<(NN + 63) / 64, 256, 0, stream>>>(selfn, nmm, WsT, WnT, s1sum, s1sq,
                                                 g1, b1, out, s2sum, s2sq);
    k_stats<<<1, 256, 0, stream>>>(s2sum, s2sq, g2, b2, 1.f / (float)NN, a2, c2);
    k7_bn_relu<<<NN * TD / 4 / 256, 256, 0, stream>>>(out, a2, c2);
}

// Round 3
// 1046.486 us; speedup vs baseline: 1.0028x; 1.0028x over previous
//
#include <hip/hip_runtime.h>

// PoolAggregator fused, MFMA (bf16 in / f32 acc) version.
// BISECT ROUND: K1 keeps {packed bf16 max/min (nmm), float4 staging}; K2/k0-side
// structural changes from the regressed round are reverted to the 997us structure
// (memset + two k_stats dispatches + scalar f2bf B-frag loads from Ws/Wn).
//   K1: x = neigh@Wt + bt, track per-node max/min over k (25 rows padded to 32)
//       plus BN1 column sums — the [1.25M,256] tensor never hits HBM.
//       max/min packed 2xbf16 into one u32 per (node,col): halves round-trip traffic.
//   k_stats: slot-reduce -> BN affine (a,c).  pool(BN(x)) = a>=0 ? a*max+c : a*min+c.
//   K2: [self@Ws | pooled@Wn] via MFMA, BN1-affine fused into A staging,
//       writes pre-BN Y to d_out + BN2 column sums.
//   k7: out = relu(a2*Y + c2) in place.

#define NN 50000
#define KN 25
#define FIN 128
#define TD 256
#define OUTD 128
#define BN_EPS 1e-3f
#define NSLOTS 64
#define K1_GRID 512
#define NGROUPS (NN / 2)   // 2 nodes per group

typedef float f32x4 __attribute__((ext_vector_type(4)));
typedef short bf16x8 __attribute__((ext_vector_type(8)));

__device__ __forceinline__ ushort f2bf(float f) {
    uint u = __builtin_bit_cast(uint, f);
    return (ushort)((u + 0x7FFFu + ((u >> 16) & 1u)) >> 16);
}
__device__ __forceinline__ uint pk2(float a, float b) {
    return (uint)f2bf(a) | ((uint)f2bf(b) << 16);
}
__device__ __forceinline__ float bflo(uint u) {   // low half -> f32
    return __builtin_bit_cast(float, u << 16);
}
__device__ __forceinline__ float bfhi(uint u) {   // high half -> f32
    return __builtin_bit_cast(float, u & 0xffff0000u);
}

// ============ K1: GEMM1 + pool-prep + BN1 stats ============
// Block: 256 thr (4 waves), persistent. Group = 2 nodes = 50 real rows,
// padded to 64 (node g at padded rows 32g..32g+31; rows 25..31 are garbage,
// masked in epilogue — MFMA rows are independent so garbage can't leak).
// LDS 64 KB exactly: Wt staged bf16 [128][256] once, B-frags -> regs,
// then region reused as 2x double-buffered A [64 rows][136] bf16 (pad +8
// breaks the 256B-stride bank alias; frag b128 pattern lands min-conflict).
__global__ __launch_bounds__(256, 2) void k1_gemm_pool(
    const float* __restrict__ neigh, const float* __restrict__ Wt,
    const float* __restrict__ bt, uint* __restrict__ nmm,
    float* __restrict__ s1sum, float* __restrict__ s1sq)
{
    __shared__ ushort lds[32768];   // 65536 B
    const int tid = threadIdx.x;
    const int wave = tid >> 6, lane = tid & 63;
    const int quad = lane >> 4, l16 = lane & 15;
    const int cbase = wave * 64;

    // ---- stage Wt -> LDS bf16, row-major [k][col] ----
    {
        const float4* w4 = (const float4*)Wt;     // 8192 float4
        #pragma unroll
        for (int i = 0; i < 32; ++i) {
            const int e = tid + i * 256;
            const int k = e >> 6, c4 = (e & 63) << 2;
            const float4 v = w4[e];
            uint* dst = (uint*)&lds[k * 256 + c4];
            dst[0] = pk2(v.x, v.y);
            dst[1] = pk2(v.z, v.w);
        }
    }
    __syncthreads();

    // ---- B-frags to regs: bf[nt][ks][j] = B[ks*32+quad*8+j][cbase+nt*16+l16] ----
    bf16x8 bf[4][4];
    #pragma unroll
    for (int nt = 0; nt < 4; ++nt) {
        const int col = cbase + nt * 16 + l16;
        #pragma unroll
        for (int ks = 0; ks < 4; ++ks) {
            #pragma unroll
            for (int j = 0; j < 8; ++j)
                bf[nt][ks][j] = (short)lds[(ks * 32 + quad * 8 + j) * 256 + col];
        }
    }
    __syncthreads();   // before A staging overwrites the B region

    float bv[4];
    #pragma unroll
    for (int n = 0; n < 4; ++n) bv[n] = bt[cbase + n * 16 + l16];

    float S[4] = {0.f, 0.f, 0.f, 0.f}, Q[4] = {0.f, 0.f, 0.f, 0.f};

    // ---- preload first group into buf 0 (float4: 1600 per group) ----
    int g = blockIdx.x;
    {
        const float4* src = (const float4*)(neigh + (size_t)g * 6400);
        #pragma unroll
        for (int i = 0; i < 7; ++i) {
            const int idx = tid + i * 256;
            if (idx < 1600) {
                const float4 v = src[idx];
                const int r = idx >> 5;
                const int pr = r + (r >= 25 ? 7 : 0);   // node1 -> padded rows 32+
                uint* dst = (uint*)&lds[pr * 136 + ((idx & 31) << 2)];
                dst[0] = pk2(v.x, v.y);
                dst[1] = pk2(v.z, v.w);
            }
        }
    }
    __syncthreads();

    int cur = 0;
    for (; g < NGROUPS; g += K1_GRID) {
        const int gn = g + K1_GRID;
        // prefetch next group's A into regs (overlaps with MFMA below)
        float4 pre[7];
        if (gn < NGROUPS) {
            const float4* src = (const float4*)(neigh + (size_t)gn * 6400);
            #pragma unroll
            for (int i = 0; i < 7; ++i) {
                const int idx = tid + i * 256;
                if (idx < 1600) pre[i] = src[idx];
            }
        }
        // ---- MFMA: 4 m-tiles x 4 n-tiles x 4 k-slices ----
        const ushort* Ab = lds + cur * 8704;
        f32x4 acc[4][4];
        #pragma unroll
        for (int m = 0; m < 4; ++m)
            #pragma unroll
            for (int n = 0; n < 4; ++n)
                acc[m][n] = (f32x4){0.f, 0.f, 0.f, 0.f};
        #pragma unroll
        for (int m = 0; m < 4; ++m) {
            bf16x8 af[4];
            #pragma unroll
            for (int ks = 0; ks < 4; ++ks)
                af[ks] = *(const bf16x8*)&Ab[(m * 16 + l16) * 136 + ks * 32 + quad * 8];
            #pragma unroll
            for (int n = 0; n < 4; ++n)
                #pragma unroll
                for (int ks = 0; ks < 4; ++ks)
                    acc[m][n] = __builtin_amdgcn_mfma_f32_16x16x32_bf16(af[ks], bf[n][ks], acc[m][n], 0, 0, 0);
        }
        // ---- epilogue: per node (m-tiles {2g,2g+1}), mask padded rows ----
        // C layout: col = lane&15, row = quad*4 + reg (m89-verified).
        // m even: rows 0..15 all real. m odd: row 16+quad*4+i valid iff quad*4+i<9.
        #pragma unroll
        for (int gi = 0; gi < 2; ++gi) {
            const int node = g * 2 + gi;
            #pragma unroll
            for (int n = 0; n < 4; ++n) {
                float mx = -3.4e38f, mn = 3.4e38f;
                #pragma unroll
                for (int i = 0; i < 4; ++i) {
                    const float v = acc[2 * gi][n][i] + bv[n];
                    mx = fmaxf(mx, v); mn = fminf(mn, v);
                    S[n] += v; Q[n] = fmaf(v, v, Q[n]);
                }
                #pragma unroll
                for (int i = 0; i < 4; ++i) {
                    if (quad * 4 + i < 9) {
                        const float v = acc[2 * gi + 1][n][i] + bv[n];
                        mx = fmaxf(mx, v); mn = fminf(mn, v);
                        S[n] += v; Q[n] = fmaf(v, v, Q[n]);
                    }
                }
                mx = fmaxf(mx, __shfl_xor(mx, 16)); mx = fmaxf(mx, __shfl_xor(mx, 32));
                mn = fminf(mn, __shfl_xor(mn, 16)); mn = fminf(mn, __shfl_xor(mn, 32));
                if (lane < 16)
                    nmm[node * TD + cbase + n * 16 + lane] = pk2(mx, mn);  // lo=max, hi=min
            }
        }
        // ---- write prefetched A into the other buffer ----
        if (gn < NGROUPS) {
            ushort* Aw = lds + (cur ^ 1) * 8704;
            #pragma unroll
            for (int i = 0; i < 7; ++i) {
                const int idx = tid + i * 256;
                if (idx < 1600) {
                    const int r = idx >> 5;
                    const int pr = r + (r >= 25 ? 7 : 0);
                    uint* dst = (uint*)&Aw[pr * 136 + ((idx & 31) << 2)];
                    dst[0] = pk2(pre[i].x, pre[i].y);
                    dst[1] = pk2(pre[i].z, pre[i].w);
                }
            }
        }
        __syncthreads();
        cur ^= 1;
    }
    // ---- flush BN1 stats (once per block) ----
    #pragma unroll
    for (int n = 0; n < 4; ++n) {
        float s = S[n]; s += __shfl_xor(s, 16); s += __shfl_xor(s, 32);
        float q = Q[n]; q += __shfl_xor(q, 16); q += __shfl_xor(q, 32);
        if (lane < 16) {
            const int col = cbase + n * 16 + lane;
            const int slot = blockIdx.x & (NSLOTS - 1);
            atomicAdd(&s1sum[slot * TD + col], s);
            atomicAdd(&s1sq[slot * TD + col], q);
        }
    }
}

// ============ slot stats -> BN affine coefficients ============
__global__ __launch_bounds__(256) void k_stats(
    const float* __restrict__ ssum, const float* __restrict__ ssq,
    const float* __restrict__ g, const float* __restrict__ b,
    float invM, float* __restrict__ a, float* __restrict__ cc)
{
    const int c = threadIdx.x;
    float s = 0.f, q = 0.f;
    for (int j = 0; j < NSLOTS; ++j) { s += ssum[j * TD + c]; q += ssq[j * TD + c]; }
    const float mean = s * invM;
    const float var = q * invM - mean * mean;
    const float A = rsqrtf(var + BN_EPS) * g[c];
    a[c] = A;
    cc[c] = fmaf(-mean, A, b[c]);
}

// ============ K2: [self@Ws | pooled@Wn] MFMA, Y (pre-BN2) -> d_out + stats ============
// Block: 64 rows, 4 waves. Waves 0,1: self GEMM (K=128); waves 2,3: pooled (K=256).
// Output col base = wave*64 (matches concat order). B-frags direct from global (L2),
// scalar f2bf loads (round-0 structure). Pooled staging reads packed nmm (u32: lo=max,
// hi=min) — half the bytes / half the load instructions of the two-f32-array version.
__global__ __launch_bounds__(256, 2) void k2_gemm2(
    const float* __restrict__ selfn, const uint* __restrict__ nmm,
    const float* __restrict__ Ws, const float* __restrict__ Wn,
    const float* __restrict__ a1, const float* __restrict__ c1,
    float* __restrict__ Y, float* __restrict__ s2sum, float* __restrict__ s2sq)
{
    __shared__ ushort lds[25600];   // As[64][136] @0 (17408B), Ap[64][264] @8704 (33792B)
    const int tid = threadIdx.x;
    const int wave = tid >> 6, lane = tid & 63;
    const int quad = lane >> 4, l16 = lane & 15;
    const int R0 = blockIdx.x * 64;

    // stage self -> As (bf16)
    {
        const float4* s4 = (const float4*)selfn;
        #pragma unroll
        for (int i = 0; i < 8; ++i) {
            const int e = tid + i * 256;          // < 2048
            const int r = e >> 5, k4 = e & 31;
            const int gr = R0 + r;
            const float4 v = (gr < NN) ? s4[(size_t)gr * 32 + k4] : make_float4(0.f, 0.f, 0.f, 0.f);
            uint* dst = (uint*)&lds[r * 136 + (k4 << 2)];
            dst[0] = pk2(v.x, v.y);
            dst[1] = pk2(v.z, v.w);
        }
    }
    // stage pooled -> Ap: pooled = a1>=0 ? a1*max+c1 : a1*min+c1, to bf16
    {
        const uint4* m4 = (const uint4*)nmm;
        const float4* a4p = (const float4*)a1;
        const float4* c4p = (const float4*)c1;
        #pragma unroll
        for (int i = 0; i < 16; ++i) {
            const int e = tid + i * 256;          // < 4096
            const int r = e >> 6, c4 = e & 63;
            const int gr = R0 + r;
            uint4 v;
            if (gr < NN) v = m4[(size_t)gr * 64 + c4];
            else { v.x = 0u; v.y = 0u; v.z = 0u; v.w = 0u; }
            const float4 a = a4p[c4], c = c4p[c4];
            const float p0 = (a.x >= 0.f) ? fmaf(a.x, bflo(v.x), c.x) : fmaf(a.x, bfhi(v.x), c.x);
            const float p1 = (a.y >= 0.f) ? fmaf(a.y, bflo(v.y), c.y) : fmaf(a.y, bfhi(v.y), c.y);
            const float p2 = (a.z >= 0.f) ? fmaf(a.z, bflo(v.z), c.z) : fmaf(a.z, bfhi(v.z), c.z);
            const float p3 = (a.w >= 0.f) ? fmaf(a.w, bflo(v.w), c.w) : fmaf(a.w, bfhi(v.w), c.w);
            uint* dst = (uint*)&lds[8704 + r * 264 + (c4 << 2)];
            dst[0] = pk2(p0, p1);
            dst[1] = pk2(p2, p3);
        }
    }
    __syncthreads();

    f32x4 acc[4][4];
    #pragma unroll
    for (int m = 0; m < 4; ++m)
        #pragma unroll
        for (int n = 0; n < 4; ++n)
            acc[m][n] = (f32x4){0.f, 0.f, 0.f, 0.f};

    if (wave < 2) {
        const int cb = wave * 64;
        bf16x8 bfr[4][4];
        #pragma unroll
        for (int nt = 0; nt < 4; ++nt)
            #pragma unroll
            for (int ks = 0; ks < 4; ++ks)
                #pragma unroll
                for (int j = 0; j < 8; ++j)
                    bfr[nt][ks][j] = (short)f2bf(Ws[(ks * 32 + quad * 8 + j) * OUTD + cb + nt * 16 + l16]);
        #pragma unroll
        for (int m = 0; m < 4; ++m) {
            bf16x8 af[4];
            #pragma unroll
            for (int ks = 0; ks < 4; ++ks)
                af[ks] = *(const bf16x8*)&lds[(m * 16 + l16) * 136 + ks * 32 + quad * 8];
            #pragma unroll
            for (int nt = 0; nt < 4; ++nt)
                #pragma unroll
                for (int ks = 0; ks < 4; ++ks)
                    acc[m][nt] = __builtin_amdgcn_mfma_f32_16x16x32_bf16(af[ks], bfr[nt][ks], acc[m][nt], 0, 0, 0);
        }
    } else {
        const int cb = (wave - 2) * 64;
        bf16x8 bfr[4][8];
        #pragma unroll
        for (int nt = 0; nt < 4; ++nt)
            #pragma unroll
            for (int ks = 0; ks < 8; ++ks)
                #pragma unroll
                for (int j = 0; j < 8; ++j)
                    bfr[nt][ks][j] = (short)f2bf(Wn[(ks * 32 + quad * 8 + j) * OUTD + cb + nt * 16 + l16]);
        #pragma unroll
        for (int m = 0; m < 4; ++m) {
            bf16x8 af[8];
            #pragma unroll
            for (int ks = 0; ks < 8; ++ks)
                af[ks] = *(const bf16x8*)&lds[8704 + (m * 16 + l16) * 264 + ks * 32 + quad * 8];
            #pragma unroll
            for (int nt = 0; nt < 4; ++nt)
                #pragma unroll
                for (int ks = 0; ks < 8; ++ks)
                    acc[m][nt] = __builtin_amdgcn_mfma_f32_16x16x32_bf16(af[ks], bfr[nt][ks], acc[m][nt], 0, 0, 0);
        }
    }

    // epilogue: Y (pre-BN2) + column stats
    const int colb = wave * 64;
    float S[4] = {0.f, 0.f, 0.f, 0.f}, Q[4] = {0.f, 0.f, 0.f, 0.f};
    #pragma unroll
    for (int m = 0; m < 4; ++m) {
        #pragma unroll
        for (int nt = 0; nt < 4; ++nt) {
            #pragma unroll
            for (int i = 0; i < 4; ++i) {
                const int row = R0 + m * 16 + quad * 4 + i;
                const float v = acc[m][nt][i];
                if (row < NN) {
                    Y[(size_t)row * TD + colb + nt * 16 + l16] = v;
                    S[nt] += v;
                    Q[nt] = fmaf(v, v, Q[nt]);
                }
            }
        }
    }
    #pragma unroll
    for (int nt = 0; nt < 4; ++nt) {
        float s = S[nt]; s += __shfl_xor(s, 16); s += __shfl_xor(s, 32);
        float q = Q[nt]; q += __shfl_xor(q, 16); q += __shfl_xor(q, 32);
        if (lane < 16) {
            const int col = colb + nt * 16 + lane;
            const int slot = blockIdx.x & (NSLOTS - 1);
            atomicAdd(&s2sum[slot * TD + col], s);
            atomicAdd(&s2sq[slot * TD + col], q);
        }
    }
}

// ============ K7: out = relu(a2*Y + c2), in place on d_out ============
__global__ __launch_bounds__(256) void k7_bn_relu(
    float* __restrict__ out, const float* __restrict__ a2, const float* __restrict__ c2)
{
    const int idx = blockIdx.x * 256 + threadIdx.x;   // float4 index, N*TD/4
    const int c4 = idx & 63;
    float4 y = ((const float4*)out)[idx];
    const float4 a = ((const float4*)a2)[c4];
    const float4 c = ((const float4*)c2)[c4];
    y.x = fmaxf(0.f, fmaf(a.x, y.x, c.x));
    y.y = fmaxf(0.f, fmaf(a.y, y.y, c.y));
    y.z = fmaxf(0.f, fmaf(a.z, y.z, c.z));
    y.w = fmaxf(0.f, fmaf(a.w, y.w, c.w));
    ((float4*)out)[idx] = y;
}

extern "C" void kernel_launch(void* const* d_in, const int* in_sizes, int n_in,
                              void* d_out, int out_size, void* d_ws, size_t ws_size,
                              hipStream_t stream) {
    const float* selfn = (const float*)d_in[0];
    const float* neigh = (const float*)d_in[1];
    // d_in[2] = len_adj_nodes: unused by the reference
    const float* Wt = (const float*)d_in[3];
    const float* bt = (const float*)d_in[4];
    const float* g1 = (const float*)d_in[5];
    const float* b1 = (const float*)d_in[6];
    const float* Wn = (const float*)d_in[7];
    const float* Ws = (const float*)d_in[8];
    const float* g2 = (const float*)d_in[9];
    const float* b2 = (const float*)d_in[10];
    float* out = (float*)d_out;

    // ws layout (floats): nmm[N*T] u32 | s1sum,s1sq,s2sum,s2sq [64*T each] | a1,c1,a2,c2
    float* ws = (float*)d_ws;
    uint* nmm = (uint*)ws;
    float* s1sum = ws + (size_t)NN * TD;
    float* s1sq = s1sum + NSLOTS * TD;
    float* s2sum = s1sq + NSLOTS * TD;
    float* s2sq = s2sum + NSLOTS * TD;
    float* a1 = s2sq + NSLOTS * TD;
    float* c1 = a1 + TD;
    float* a2 = c1 + TD;
    float* c2 = a2 + TD;

    hipMemsetAsync(s1sum, 0, (size_t)4 * NSLOTS * TD * sizeof(float), stream);

    k1_gemm_pool<<<K1_GRID, 256, 0, stream>>>(neigh, Wt, bt, nmm, s1sum, s1sq);
    k_stats<<<1, 256, 0, stream>>>(s1sum, s1sq, g1, b1, 1.f / (float)(NN * KN), a1, c1);
    k2_gemm2<<<(NN + 63) / 64, 256, 0, stream>>>(selfn, nmm, Ws, Wn, a1, c1, out, s2sum, s2sq);
    k_stats<<<1, 256, 0, stream>>>(s2sum, s2sq, g2, b2, 1.f / (float)NN, a2, c2);
    k7_bn_relu<<<NN * TD / 4 / 256, 256, 0, stream>>>(out, a2, c2);
}